// Round 5
// baseline (449.626 us; speedup 1.0000x reference)
//
#include <hip/hip_runtime.h>

#define NL 128          // N_LABELS
#define TT 512          // T
#define NB 512          // B
#define START_IDX 126
#define STOP_IDX 127

typedef __attribute__((ext_vector_type(8))) short bf16x8;
typedef __attribute__((ext_vector_type(4))) float f32x4;
typedef __attribute__((ext_vector_type(4))) unsigned u32x4;

__device__ __forceinline__ short f2bf(float x) {
    union { float f; unsigned u; } v; v.f = x;
    unsigned r = (v.u + 0x7FFFu + ((v.u >> 16) & 1u)) >> 16;  // RNE
    return (short)r;
}

__device__ __forceinline__ unsigned cvt_pk_bf16(float lo, float hi) {
    unsigned r;
    asm("v_cvt_pk_bf16_f32 %0, %1, %2" : "=v"(r) : "v"(lo), "v"(hi));
    return r;   // low half <- lo, high half <- hi
}

// ---------------------------------------------------------------------------
// Pass 1: EL[b][t][q*4+j] = exp(logits[b][t][lbl(q,j)]), lbl = (q&7)*16+(q>>3)*4+j.
// ---------------------------------------------------------------------------
__global__ __launch_bounds__(256)
void exp_pre(const float* __restrict__ logits, const int* __restrict__ lens,
             float* __restrict__ elp)
{
    const int b = blockIdx.x;
    int len = lens[b]; len = len < 1 ? 1 : (len > TT ? TT : len);
    const float* src = logits + (size_t)b * TT * NL;
    float*       dst = elp    + (size_t)b * TT * NL;
    for (int idx = threadIdx.x; idx < len * 32; idx += 256) {
        const int t = idx >> 5, q = idx & 31;
        const int lbl = (q & 7) * 16 + (q >> 3) * 4;
        f32x4 v = *(const f32x4*)(src + t * NL + lbl);
        f32x4 e = { __expf(v[0]), __expf(v[1]), __expf(v[2]), __expf(v[3]) };
        *(f32x4*)(dst + t * NL + q * 4) = e;
    }
}

// ---------------------------------------------------------------------------
// Pass 2: one wave per 16 batches (MFMA columns). Zero LDS, zero barriers.
//   A[R][K] = exp(trans[R][phi(K)]), phi(kk*32+8g+j) = (kk+4*(j>>2))*16+4g+(j&3)
//   B[K][c] = v_c[phi(K)] ; C[R][c] = u_c[R], R = m*16+4g+reg.
// The phi twist makes the C-frag exactly next step's B-frag (per-lane).
// el loaded in-step (latency hides under the 32-MFMA issue block).
// Per-batch (per-c) exact power-of-2 rescale every 8 steps; per-batch freeze
// at t==lenc via predicated bw/cbi updates.
// ---------------------------------------------------------------------------
#define LOADE(E_, T_) do {                                                    \
    const float* _p = elsrc + (size_t)(T_) * NL;                              \
    _Pragma("unroll") for (int m_ = 0; m_ < 8; ++m_) {                        \
        const int off_ = RAW ? (m_ * 16 + 4 * g) : (g * 32 + m_ * 4);         \
        E_[m_] = *(const f32x4*)(_p + off_);                                  \
    }                                                                         \
} while (0)

#define SNAPB(BV_) do {                                                       \
    _Pragma("unroll") for (int kk_ = 0; kk_ < 4; ++kk_) {                     \
        u32x4 bu_ = { bw[kk_][0], bw[kk_][1], bw[kk_][2], bw[kk_][3] };       \
        BV_[kk_] = __builtin_bit_cast(bf16x8, bu_);                           \
    }                                                                         \
} while (0)

// Normal step: pair-grouped so each bw word-group's VALU interleaves with the
// next pair's MFMA issue.
#define STEP_N(T_) do {                                                       \
    f32x4 E_[8]; LOADE(E_, T_);                                               \
    const bool live_ = (T_) < lenc;                                           \
    bf16x8 bv_[4]; SNAPB(bv_);                                                \
    _Pragma("unroll") for (int p_ = 0; p_ < 4; ++p_) {                        \
        f32x4 a0_ = {0.f,0.f,0.f,0.f}, a1_ = {0.f,0.f,0.f,0.f};               \
        _Pragma("unroll") for (int kk_ = 0; kk_ < 4; ++kk_) {                 \
            a0_ = __builtin_amdgcn_mfma_f32_16x16x32_bf16(afr[p_][kk_],     bv_[kk_], a0_, 0,0,0); \
            a1_ = __builtin_amdgcn_mfma_f32_16x16x32_bf16(afr[p_ + 4][kk_], bv_[kk_], a1_, 0,0,0); \
        }                                                                     \
        float n0_[4], n1_[4];                                                 \
        _Pragma("unroll") for (int r_ = 0; r_ < 4; ++r_) {                    \
            float e0_ = E_[p_][r_], e1_ = E_[p_ + 4][r_];                     \
            if (RAW) { e0_ = __expf(e0_); e1_ = __expf(e1_); }                \
            n0_[r_] = a0_[r_] * e0_; n1_[r_] = a1_[r_] * e1_;                 \
        }                                                                     \
        if (live_) {                                                          \
            bw[p_][0] = cvt_pk_bf16(n0_[0], n0_[1]);                          \
            bw[p_][1] = cvt_pk_bf16(n0_[2], n0_[3]);                          \
            bw[p_][2] = cvt_pk_bf16(n1_[0], n1_[1]);                          \
            bw[p_][3] = cvt_pk_bf16(n1_[2], n1_[3]);                          \
        }                                                                     \
    }                                                                         \
} while (0)

// Rescale step: needs all nv before the per-batch max.
#define STEP_R(T_) do {                                                       \
    f32x4 E_[8]; LOADE(E_, T_);                                               \
    const bool live_ = (T_) < lenc;                                           \
    bf16x8 bv_[4]; SNAPB(bv_);                                                \
    f32x4 acc_[8];                                                            \
    _Pragma("unroll") for (int m_ = 0; m_ < 8; ++m_)                          \
        acc_[m_] = (f32x4){0.f,0.f,0.f,0.f};                                  \
    _Pragma("unroll") for (int kk_ = 0; kk_ < 4; ++kk_)                       \
        _Pragma("unroll") for (int m_ = 0; m_ < 8; ++m_)                      \
            acc_[m_] = __builtin_amdgcn_mfma_f32_16x16x32_bf16(               \
                afr[m_][kk_], bv_[kk_], acc_[m_], 0, 0, 0);                   \
    float nv_[8][4];                                                          \
    _Pragma("unroll") for (int m_ = 0; m_ < 8; ++m_)                          \
        _Pragma("unroll") for (int r_ = 0; r_ < 4; ++r_) {                    \
            float el_ = E_[m_][r_];                                           \
            if (RAW) el_ = __expf(el_);                                       \
            nv_[m_][r_] = acc_[m_][r_] * el_;                                 \
        }                                                                     \
    float mx_ = nv_[0][0];                                                    \
    _Pragma("unroll") for (int m_ = 0; m_ < 8; ++m_)                          \
        _Pragma("unroll") for (int r_ = 0; r_ < 4; ++r_)                      \
            mx_ = fmaxf(mx_, nv_[m_][r_]);                                    \
    mx_ = fmaxf(mx_, __shfl_xor(mx_, 16));                                    \
    mx_ = fmaxf(mx_, __shfl_xor(mx_, 32));                                    \
    const unsigned eb_ = (__float_as_uint(mx_) >> 23) & 0xFFu;                \
    const float sc_ = __uint_as_float(((253u - eb_) & 0xFFu) << 23);          \
    _Pragma("unroll") for (int m_ = 0; m_ < 8; ++m_)                          \
        _Pragma("unroll") for (int r_ = 0; r_ < 4; ++r_)                      \
            nv_[m_][r_] *= sc_;                                               \
    if (live_) {                                                              \
        cbi += (int)eb_ - 126;                                                \
        _Pragma("unroll") for (int kk_ = 0; kk_ < 4; ++kk_) {                 \
            bw[kk_][0] = cvt_pk_bf16(nv_[kk_][0],     nv_[kk_][1]);           \
            bw[kk_][1] = cvt_pk_bf16(nv_[kk_][2],     nv_[kk_][3]);           \
            bw[kk_][2] = cvt_pk_bf16(nv_[kk_ + 4][0], nv_[kk_ + 4][1]);       \
            bw[kk_][3] = cvt_pk_bf16(nv_[kk_ + 4][2], nv_[kk_ + 4][3]);       \
        }                                                                     \
    }                                                                         \
} while (0)

template<bool RAW>
__global__ __launch_bounds__(64, 1)
void crf_scan(const float* __restrict__ logits,
              const int* __restrict__ lens,
              const float* __restrict__ trans,
              const float* __restrict__ elp,
              float* __restrict__ out)
{
    const int b0   = blockIdx.x * 16;
    const int lane = threadIdx.x;
    const int c    = lane & 15;          // batch within group / A row / C col
    const int g    = lane >> 4;          // k-group

    // ---- A fragments: afr[m][kk], lane holds A[m*16+c][kk*32+8g+j] ----
    bf16x8 afr[8][4];
    #pragma unroll
    for (int m = 0; m < 8; ++m) {
        const float* rowp = trans + (m * 16 + c) * NL + 4 * g;
        #pragma unroll
        for (int kk = 0; kk < 4; ++kk) {
            f32x4 lo4 = *(const f32x4*)(rowp + kk * 16);        // phi: j=0..3
            f32x4 hi4 = *(const f32x4*)(rowp + (kk + 4) * 16);  // phi: j=4..7
            bf16x8 a;
            #pragma unroll
            for (int j = 0; j < 4; ++j) {
                a[j]     = f2bf(__expf(lo4[j]));
                a[j + 4] = f2bf(__expf(hi4[j]));
            }
            afr[m][kk] = a;
        }
    }

    int lenc = lens[b0 + c];
    lenc = lenc < 1 ? 1 : (lenc > TT ? TT : lenc);
    int gl = lenc;
    #pragma unroll
    for (int d = 1; d < 16; d <<= 1) { int o = __shfl_xor(gl, d); gl = gl > o ? gl : o; }
    const int glen = __builtin_amdgcn_readfirstlane(gl);

    // ---- B registers: packed bf16 pairs; one-hot at START (=label 126) ----
    // phi^-1(126): kk=3, j=6 on g==3 lanes -> word 3, low half.
    unsigned bw[4][4];
    #pragma unroll
    for (int kk = 0; kk < 4; ++kk)
        #pragma unroll
        for (int i = 0; i < 4; ++i) bw[kk][i] = 0u;
    if (g == 3) bw[3][3] = 0x00003F80u;

    int cbi = 0;                         // per-batch rescale exponent count
    const float* elsrc = (RAW ? logits : elp) + (size_t)(b0 + c) * TT * NL;

    int t = 0;
    const int tmain = glen & ~7;
    for (; t < tmain; t += 8) {
        STEP_N(t + 0);
        STEP_N(t + 1);
        STEP_N(t + 2);
        STEP_N(t + 3);
        STEP_N(t + 4);
        STEP_N(t + 5);
        STEP_N(t + 6);
        STEP_R(t + 7);                   // rescale every 8 steps (exact)
    }
    if (t < glen) { STEP_N(t); ++t; }
    if (t < glen) { STEP_N(t); ++t; }
    if (t < glen) { STEP_N(t); ++t; }
    if (t < glen) { STEP_N(t); ++t; }
    if (t < glen) { STEP_N(t); ++t; }
    if (t < glen) { STEP_N(t); ++t; }
    if (t < glen) { STEP_N(t); ++t; }

    // ---- out[b] = cbi*ln2 + log( sum_L v[L] * exp(trans[STOP][L]) ) ----
    float s = 0.f;
    const float* stopr = trans + STOP_IDX * NL + 4 * g;
    #pragma unroll
    for (int kk = 0; kk < 4; ++kk) {
        f32x4 t0 = *(const f32x4*)(stopr + kk * 16);
        f32x4 t1 = *(const f32x4*)(stopr + (kk + 4) * 16);
        #pragma unroll
        for (int i = 0; i < 2; ++i) {
            const unsigned w = bw[kk][i];
            s += __uint_as_float(w << 16)          * __expf(t0[2 * i]);
            s += __uint_as_float(w & 0xFFFF0000u)  * __expf(t0[2 * i + 1]);
        }
        #pragma unroll
        for (int i = 2; i < 4; ++i) {
            const unsigned w = bw[kk][i];
            s += __uint_as_float(w << 16)          * __expf(t1[2 * (i - 2)]);
            s += __uint_as_float(w & 0xFFFF0000u)  * __expf(t1[2 * (i - 2) + 1]);
        }
    }
    s += __shfl_xor(s, 16);
    s += __shfl_xor(s, 32);
    if (lane < 16)
        out[b0 + c] = (float)cbi * 0.69314718055994531f + __logf(s);
}

extern "C" void kernel_launch(void* const* d_in, const int* in_sizes, int n_in,
                              void* d_out, int out_size, void* d_ws, size_t ws_size,
                              hipStream_t stream) {
    const float* logits = (const float*)d_in[0];
    const int*   lens   = (const int*)d_in[1];
    const float* trans  = (const float*)d_in[2];
    float*       outp   = (float*)d_out;

    const size_t need = (size_t)NB * TT * NL * sizeof(float);
    if (ws_size >= need) {
        float* elp = (float*)d_ws;
        exp_pre<<<NB, 256, 0, stream>>>(logits, lens, elp);
        crf_scan<false><<<NB / 16, 64, 0, stream>>>(logits, lens, trans, elp, outp);
    } else {
        crf_scan<true><<<NB / 16, 64, 0, stream>>>(logits, lens, trans, nullptr, outp);
    }
}

// Round 6
// 177.804 us; speedup vs baseline: 2.5288x; 2.5288x over previous
//
#include <hip/hip_runtime.h>

#define NL 128          // N_LABELS
#define TT 512          // T
#define NB 512          // B
#define START_IDX 126
#define STOP_IDX 127

typedef __attribute__((ext_vector_type(8))) short bf16x8;
typedef __attribute__((ext_vector_type(4))) float f32x4;
typedef __attribute__((ext_vector_type(4))) unsigned u32x4;

__device__ __forceinline__ short f2bf(float x) {
    union { float f; unsigned u; } v; v.f = x;
    unsigned r = (v.u + 0x7FFFu + ((v.u >> 16) & 1u)) >> 16;  // RNE
    return (short)r;
}

__device__ __forceinline__ unsigned cvt_pk_bf16(float lo, float hi) {
    unsigned r;
    asm("v_cvt_pk_bf16_f32 %0, %1, %2" : "=v"(r) : "v"(lo), "v"(hi));
    return r;   // low half <- lo, high half <- hi
}

// ---------------------------------------------------------------------------
// One block = 16 batches (MFMA columns). 4 waves; wave w owns m-tiles {w, w+4}.
//   A[R][K] = exp(trans[R][phi(K)]), phi(kk*32+8g+j) = (kk+4*(j>>2))*16+4g+(j&3)
//   B[K][c] = v_c[phi(K)] ; C[R][c] = u_c[R], R = m*16+4g+reg.
// phi makes wave w's two C-frags exactly B-word-group kk=w (same lane), so the
// per-step exchange is 1x ds_write_b128 + 3x ds_read_b128 through a stride-80
// double-buffered LDS (conflict-free), one barrier per step.
// logits loaded 2 steps ahead, exp'd 1 step ahead (off the serial chain).
// Lag-1 cross-wave max (publish t%4==2, consume t%4==3) -> exact 2^k rescale.
// Per-batch freeze at t==lenc: keep-old cndmask on the published words.
// ---------------------------------------------------------------------------
#define STEP(T_, PUB_, CONS_, EC_, EO_, RC_, RO_) do {                        \
    u32x4 bo_ = {bw0, bw1, bw2, bw3};                                         \
    bf16x8 bO_ = __builtin_bit_cast(bf16x8, bo_);                             \
    bf16x8 bA_ = __builtin_bit_cast(bf16x8, bvA);                             \
    bf16x8 bB_ = __builtin_bit_cast(bf16x8, bvB);                             \
    bf16x8 bC_ = __builtin_bit_cast(bf16x8, bvC);                             \
    f32x4 a0_ = {0.f,0.f,0.f,0.f}, a1_ = {0.f,0.f,0.f,0.f};                   \
    a0_ = __builtin_amdgcn_mfma_f32_16x16x32_bf16(afr[0][0], bO_, a0_, 0,0,0);\
    a1_ = __builtin_amdgcn_mfma_f32_16x16x32_bf16(afr[1][0], bO_, a1_, 0,0,0);\
    a0_ = __builtin_amdgcn_mfma_f32_16x16x32_bf16(afr[0][1], bA_, a0_, 0,0,0);\
    a1_ = __builtin_amdgcn_mfma_f32_16x16x32_bf16(afr[1][1], bA_, a1_, 0,0,0);\
    a0_ = __builtin_amdgcn_mfma_f32_16x16x32_bf16(afr[0][2], bB_, a0_, 0,0,0);\
    a1_ = __builtin_amdgcn_mfma_f32_16x16x32_bf16(afr[1][2], bB_, a1_, 0,0,0);\
    a0_ = __builtin_amdgcn_mfma_f32_16x16x32_bf16(afr[0][3], bC_, a0_, 0,0,0);\
    a1_ = __builtin_amdgcn_mfma_f32_16x16x32_bf16(afr[1][3], bC_, a1_, 0,0,0);\
    { int tp_ = (T_) + 2; if (tp_ > TT - 1) tp_ = TT - 1;                     \
      const float* lp_ = lsrc + (size_t)tp_ * NL;                             \
      RC_##0 = *(const f32x4*)(lp_ + eo0);                                    \
      RC_##1 = *(const f32x4*)(lp_ + eo1); }                                  \
    _Pragma("unroll")                                                         \
    for (int r_ = 0; r_ < 4; ++r_) {                                          \
        EO_##0[r_] = __expf(RO_##0[r_]);                                      \
        EO_##1[r_] = __expf(RO_##1[r_]);                                      \
    }                                                                         \
    float nv0_[4], nv1_[4];                                                   \
    _Pragma("unroll")                                                         \
    for (int r_ = 0; r_ < 4; ++r_) {                                          \
        nv0_[r_] = a0_[r_] * EC_##0[r_];                                      \
        nv1_[r_] = a1_[r_] * EC_##1[r_];                                      \
    }                                                                         \
    const bool live_ = (T_) < lenc;                                           \
    if (CONS_) {                                                              \
        float mx_ = fmaxf(fmaxf(smax[0][c], smax[1][c]),                      \
                          fmaxf(smax[2][c], smax[3][c]));                     \
        const unsigned eb_ = (__float_as_uint(mx_) >> 23) & 0xFFu;            \
        const float sc_ = __uint_as_float(((253u - eb_) & 0xFFu) << 23);      \
        _Pragma("unroll")                                                     \
        for (int r_ = 0; r_ < 4; ++r_) { nv0_[r_] *= sc_; nv1_[r_] *= sc_; }  \
        if (live_) cbi += (int)eb_ - 126;                                     \
    }                                                                         \
    if (PUB_) {                                                               \
        float lm_ = fmaxf(fmaxf(fmaxf(nv0_[0], nv0_[1]), fmaxf(nv0_[2], nv0_[3])), \
                          fmaxf(fmaxf(nv1_[0], nv1_[1]), fmaxf(nv1_[2], nv1_[3]))); \
        lm_ = fmaxf(lm_, __shfl_xor(lm_, 16));                                \
        lm_ = fmaxf(lm_, __shfl_xor(lm_, 32));                                \
        if (g == 0) smax[w][c] = lm_;                                         \
    }                                                                         \
    { const unsigned n0_ = cvt_pk_bf16(nv0_[0], nv0_[1]);                     \
      const unsigned n1_ = cvt_pk_bf16(nv0_[2], nv0_[3]);                     \
      const unsigned n2_ = cvt_pk_bf16(nv1_[0], nv1_[1]);                     \
      const unsigned n3_ = cvt_pk_bf16(nv1_[2], nv1_[3]);                     \
      bw0 = live_ ? n0_ : bw0;  bw1 = live_ ? n1_ : bw1;                      \
      bw2 = live_ ? n2_ : bw2;  bw3 = live_ ? n3_ : bw3; }                    \
    char* nb_ = sb[((T_) + 1) & 1];                                           \
    { u32x4 wv_ = {bw0, bw1, bw2, bw3};                                       \
      *(u32x4*)(nb_ + w * 1280 + slotOff) = wv_; }                            \
    __syncthreads();                                                          \
    bvA = *(const u32x4*)(nb_ + kA + slotOff);                                \
    bvB = *(const u32x4*)(nb_ + kB + slotOff);                                \
    bvC = *(const u32x4*)(nb_ + kC + slotOff);                                \
} while (0)

__global__ __launch_bounds__(256)
void crf_scan(const float* __restrict__ logits,
              const int* __restrict__ lens,
              const float* __restrict__ trans,
              float* __restrict__ out)
{
    const int b0   = blockIdx.x * 16;
    const int tid  = threadIdx.x;
    const int w    = tid >> 6;           // wave: owns m-tiles {w, w+4} = group kk=w
    const int lane = tid & 63;
    const int c    = lane & 15;          // batch / A row within tile / C col
    const int g    = lane >> 4;          // k-group

    // slot(kk,c,g) = kk*1280 + c*80 + g*16 (stride 80 -> conflict-free b128)
    __shared__ __align__(16) char sb[2][4 * 16 * 80];
    __shared__ float smax[4][16];

    // ---- A fragments, chain-ordered: pos -> logical kk = (w+pos)&3 ----
    bf16x8 afr[2][4];
    #pragma unroll
    for (int mi = 0; mi < 2; ++mi) {
        const int M = w + 4 * mi;
        const float* rowp = trans + (M * 16 + c) * NL + 4 * g;
        #pragma unroll
        for (int pos = 0; pos < 4; ++pos) {
            const int kk = (w + pos) & 3;
            f32x4 lo4 = *(const f32x4*)(rowp + kk * 16);        // e=0..3
            f32x4 hi4 = *(const f32x4*)(rowp + (kk + 4) * 16);  // e=4..7
            bf16x8 a;
            #pragma unroll
            for (int j = 0; j < 4; ++j) {
                a[j]     = f2bf(__expf(lo4[j]));
                a[j + 4] = f2bf(__expf(hi4[j]));
            }
            afr[mi][pos] = a;
        }
    }

    int lenc = lens[b0 + c];
    lenc = lenc < 1 ? 1 : (lenc > TT ? TT : lenc);
    int gl = lenc;
    #pragma unroll
    for (int d = 1; d < 16; d <<= 1) { int o = __shfl_xor(gl, d); gl = gl > o ? gl : o; }
    const int glen = __builtin_amdgcn_readfirstlane(gl);

    const int slotOff = c * 80 + g * 16;
    const int kA = ((w + 1) & 3) * 1280;
    const int kB = ((w + 2) & 3) * 1280;
    const int kC = ((w + 3) & 3) * 1280;

    // ---- init: v0 one-hot at START(126) -> group kk=3, g=3, word 3, low half
    unsigned bw0 = 0u, bw1 = 0u, bw2 = 0u,
             bw3 = (w == 3 && g == 3) ? 0x00003F80u : 0u;
    { u32x4 z = {bw0, bw1, bw2, bw3};
      *(u32x4*)(sb[0] + w * 1280 + slotOff) = z; }
    __syncthreads();
    u32x4 bvA = *(const u32x4*)(sb[0] + kA + slotOff);
    u32x4 bvB = *(const u32x4*)(sb[0] + kB + slotOff);
    u32x4 bvC = *(const u32x4*)(sb[0] + kC + slotOff);

    const float* lsrc = logits + (size_t)(b0 + c) * TT * NL;
    const int eo0 = w * 16 + 4 * g;          // labels of m-tile w
    const int eo1 = (w + 4) * 16 + 4 * g;    // labels of m-tile w+4

    // el pipeline: raw loaded 2 steps ahead, exp'd 1 step ahead
    f32x4 R00, R01, R10, R11, E00, E01, E10, E11;
    R00 = *(const f32x4*)(lsrc + eo0);            R01 = *(const f32x4*)(lsrc + eo1);
    R10 = *(const f32x4*)(lsrc + NL + eo0);       R11 = *(const f32x4*)(lsrc + NL + eo1);
    #pragma unroll
    for (int r = 0; r < 4; ++r) {
        E00[r] = __expf(R00[r]); E01[r] = __expf(R01[r]);
        E10[r] = __expf(R10[r]); E11[r] = __expf(R11[r]);
    }

    int cbi = 0;
    int t = 0;
    for (; t + 4 <= glen; t += 4) {
        STEP(t + 0, false, false, E0, E1, R0, R1);
        STEP(t + 1, false, false, E1, E0, R1, R0);
        STEP(t + 2, true,  false, E0, E1, R0, R1);
        STEP(t + 3, false, true,  E1, E0, R1, R0);
    }
    for (; t < glen; ++t) {
        const bool pub = (t & 3) == 2, cons = (t & 3) == 3;
        if (t & 1) STEP(t, pub, cons, E1, E0, R1, R0);
        else       STEP(t, pub, cons, E0, E1, R0, R1);
    }

    // ---- epilogue (wave 0): final B-groups are bw(kk=0) + bvA/bvB/bvC (kk=1,2,3)
    if (w == 0) {
        float s = 0.f;
        const float* stopr = trans + STOP_IDX * NL + 4 * g;
        u32x4 grp[4];
        grp[0] = (u32x4){bw0, bw1, bw2, bw3};
        grp[1] = bvA; grp[2] = bvB; grp[3] = bvC;
        #pragma unroll
        for (int kk = 0; kk < 4; ++kk) {
            f32x4 t0 = *(const f32x4*)(stopr + kk * 16);
            f32x4 t1 = *(const f32x4*)(stopr + (kk + 4) * 16);
            #pragma unroll
            for (int i = 0; i < 2; ++i) {
                const unsigned wd = grp[kk][i];
                s += __uint_as_float(wd << 16)         * __expf(t0[2 * i]);
                s += __uint_as_float(wd & 0xFFFF0000u) * __expf(t0[2 * i + 1]);
            }
            #pragma unroll
            for (int i = 2; i < 4; ++i) {
                const unsigned wd = grp[kk][i];
                s += __uint_as_float(wd << 16)         * __expf(t1[2 * (i - 2)]);
                s += __uint_as_float(wd & 0xFFFF0000u) * __expf(t1[2 * (i - 2) + 1]);
            }
        }
        s += __shfl_xor(s, 16);
        s += __shfl_xor(s, 32);
        if (g == 0)
            out[b0 + c] = (float)cbi * 0.69314718055994531f + __logf(s);
    }
}

extern "C" void kernel_launch(void* const* d_in, const int* in_sizes, int n_in,
                              void* d_out, int out_size, void* d_ws, size_t ws_size,
                              hipStream_t stream) {
    const float* logits = (const float*)d_in[0];
    const int*   lens   = (const int*)d_in[1];
    const float* trans  = (const float*)d_in[2];
    float*       outp   = (float*)d_out;
    crf_scan<<<NB / 16, 256, 0, stream>>>(logits, lens, trans, outp);
}